// Round 1
// baseline (7699.135 us; speedup 1.0000x reference)
//
#include <hip/hip_runtime.h>
#include <math.h>

// ---------------------------------------------------------------------------
// SlotClassifier full-network port, pure f32.
// tokens buffer (B x 196 x 64 f32) lives in d_ws.
// ---------------------------------------------------------------------------

#define NTOK 196
#define DMODEL 64

// XOR swizzle for 64-float rows: quad index ^= (row & 15). Conflict-free for
// both row-broadcast float4 reads and cross-row (lane=row) accesses.
__device__ __forceinline__ int SWi(int row, int col) {
  return (row << 6) | (((((col >> 2) ^ row) & 15)) << 2) | (col & 3);
}
__device__ __forceinline__ int SW4i(int row, int q) {
  return (row << 6) | ((((q ^ row) & 15)) << 2);
}
// Same for 32-float rows (FFN hidden / W2 slice).
__device__ __forceinline__ int SHi(int row, int col) {
  return (row << 5) | (((((col >> 2) ^ row) & 7)) << 2) | (col & 3);
}
__device__ __forceinline__ int SH4i(int row, int q) {
  return (row << 5) | ((((q ^ row) & 7)) << 2);
}

__device__ __forceinline__ float gelu_exact(float v) {
  return 0.5f * v * (1.0f + erff(v * 0.7071067811865476f));
}

// ---------------------------------------------------------------------------
// Kernel A: conv1 (1->150, k9 s2 p4) + exact gelu + 1x1 proj to 64
// one block per image, 256 threads
// ---------------------------------------------------------------------------
__global__ __launch_bounds__(256) void k_conv_proj(
    const float* __restrict__ x, const float* __restrict__ conv_w,
    const float* __restrict__ proj_w, const float* __restrict__ proj_b,
    float* __restrict__ tokens) {
  __shared__ float xs[784];        // 28x28 input
  __shared__ float wsT[81 * 32];   // conv weights chunk, [tap][ch]
  __shared__ float hb[196 * 36];   // conv+gelu chunk, stride 36 (pad)
  __shared__ float pw[32 * 65];    // proj weights chunk, [ch][dc], stride 65

  const int b = blockIdx.x;
  const int tid = threadIdx.x;

  for (int i = tid; i < 784; i += 256) xs[i] = x[b * 784 + i];

  const int dc0 = (tid & 31) * 2;  // proj: this thread's dchannel pair
  const int t0 = tid >> 5;         // proj: token offset 0..7
  float acc[25][2];
#pragma unroll
  for (int j = 0; j < 25; ++j) { acc[j][0] = 0.f; acc[j][1] = 0.f; }

  const int cq = tid & 7;   // conv: channel quad 0..7
  const int pxg = tid >> 3; // conv: pixel-pair group 0..31

  for (int cc = 0; cc < 160; cc += 32) {
    __syncthreads();
    // stage conv weights transposed
    for (int i = tid; i < 81 * 32; i += 256) {
      int ch = i & 31, tap = i >> 5;
      int gch = cc + ch;
      wsT[tap * 32 + ch] = (gch < 150) ? conv_w[gch * 81 + tap] : 0.f;
    }
    // stage proj weights [ch][dc] stride 65 (bank-conflict-free both ways)
    for (int i = tid; i < 2048; i += 256) {
      int ch = i & 31, d = i >> 5;
      int gch = cc + ch;
      pw[ch * 65 + d] = (gch < 150) ? proj_w[d * 150 + gch] : 0.f;
    }
    __syncthreads();
    // conv + gelu: 2 pixels x 4 channels per thread-item
    for (int pp = 0; pp < 4; ++pp) {
      int p = pxg + 32 * pp;
      if (p < 98) {
        int px0 = 2 * p, px1 = 2 * p + 1;
        int oy0 = px0 / 14, ox0 = px0 - oy0 * 14;
        int oy1 = px1 / 14, ox1 = px1 - oy1 * 14;
        int iy0 = oy0 * 2 - 4, ix0 = ox0 * 2 - 4;
        int iy1 = oy1 * 2 - 4, ix1 = ox1 * 2 - 4;
        float a00 = 0.f, a01 = 0.f, a02 = 0.f, a03 = 0.f;
        float a10 = 0.f, a11 = 0.f, a12 = 0.f, a13 = 0.f;
        for (int ky = 0; ky < 9; ++ky) {
          int y0 = iy0 + ky, y1 = iy1 + ky;
          bool vy0 = (unsigned)y0 < 28u, vy1 = (unsigned)y1 < 28u;
          if (!vy0 && !vy1) continue;
#pragma unroll
          for (int kx = 0; kx < 9; ++kx) {
            float4 w = *(const float4*)&wsT[(ky * 9 + kx) * 32 + cq * 4];
            int x0i = ix0 + kx, x1i = ix1 + kx;
            if (vy0 && (unsigned)x0i < 28u) {
              float xv = xs[y0 * 28 + x0i];
              a00 += xv * w.x; a01 += xv * w.y; a02 += xv * w.z; a03 += xv * w.w;
            }
            if (vy1 && (unsigned)x1i < 28u) {
              float xv = xs[y1 * 28 + x1i];
              a10 += xv * w.x; a11 += xv * w.y; a12 += xv * w.z; a13 += xv * w.w;
            }
          }
        }
        int hb0 = px0 * 36 + cq * 4;
        hb[hb0 + 0] = gelu_exact(a00); hb[hb0 + 1] = gelu_exact(a01);
        hb[hb0 + 2] = gelu_exact(a02); hb[hb0 + 3] = gelu_exact(a03);
        int hb1 = px1 * 36 + cq * 4;
        hb[hb1 + 0] = gelu_exact(a10); hb[hb1 + 1] = gelu_exact(a11);
        hb[hb1 + 2] = gelu_exact(a12); hb[hb1 + 3] = gelu_exact(a13);
      }
    }
    __syncthreads();
    // proj accumulate: dc pair x 25 tokens
    for (int cv = 0; cv < 8; ++cv) {
      float w00 = pw[(cv * 4 + 0) * 65 + dc0], w01 = pw[(cv * 4 + 0) * 65 + dc0 + 1];
      float w10 = pw[(cv * 4 + 1) * 65 + dc0], w11 = pw[(cv * 4 + 1) * 65 + dc0 + 1];
      float w20 = pw[(cv * 4 + 2) * 65 + dc0], w21 = pw[(cv * 4 + 2) * 65 + dc0 + 1];
      float w30 = pw[(cv * 4 + 3) * 65 + dc0], w31 = pw[(cv * 4 + 3) * 65 + dc0 + 1];
#pragma unroll
      for (int j = 0; j < 25; ++j) {
        int t = t0 + 8 * j;
        if (t < 196) {
          float4 hq = *(const float4*)&hb[t * 36 + cv * 4];
          acc[j][0] += hq.x * w00 + hq.y * w10 + hq.z * w20 + hq.w * w30;
          acc[j][1] += hq.x * w01 + hq.y * w11 + hq.z * w21 + hq.w * w31;
        }
      }
    }
  }
  float pb0 = proj_b[dc0], pb1 = proj_b[dc0 + 1];
#pragma unroll
  for (int j = 0; j < 25; ++j) {
    int t = t0 + 8 * j;
    if (t < 196) {
      size_t o = (size_t)b * 12544 + (size_t)t * 64 + dc0;
      tokens[o] = acc[j][0] + pb0;
      tokens[o + 1] = acc[j][1] + pb1;
    }
  }
}

// ---------------------------------------------------------------------------
// Kernel B: pre-norm transformer encoder layer + final LN (in-place on tokens)
// one block per image, 512 threads, 163,072 B dynamic LDS
// ---------------------------------------------------------------------------
__device__ __forceinline__ void ln_stats_sw(const float* __restrict__ buf,
                                            float* __restrict__ MU,
                                            float* __restrict__ RS, int tid) {
  if (tid < 196) {
    float s = 0.f;
#pragma unroll
    for (int q = 0; q < 16; ++q) {
      float4 v = *(const float4*)&buf[SW4i(tid, q)];
      s += v.x + v.y + v.z + v.w;
    }
    float mu = s * 0.015625f;
    float vs = 0.f;
#pragma unroll
    for (int q = 0; q < 16; ++q) {
      float4 v = *(const float4*)&buf[SW4i(tid, q)];
      float a = v.x - mu, b = v.y - mu, c = v.z - mu, d = v.w - mu;
      vs += a * a + b * b + c * c + d * d;
    }
    MU[tid] = mu;
    RS[tid] = rsqrtf(vs * 0.015625f + 1e-5f);
  }
}

__global__ __launch_bounds__(512) void k_xformer(
    float* __restrict__ tokens,
    const float* __restrict__ ln1_g, const float* __restrict__ ln1_b,
    const float* __restrict__ Wqkv, const float* __restrict__ bqkv,
    const float* __restrict__ Wo, const float* __restrict__ bo,
    const float* __restrict__ ln2_g, const float* __restrict__ ln2_b,
    const float* __restrict__ W1, const float* __restrict__ b1,
    const float* __restrict__ W2, const float* __restrict__ b2,
    const float* __restrict__ tln_g, const float* __restrict__ tln_b) {
  extern __shared__ float smx[];
  float* T0 = smx;            // 12544, residual stream, swizzled
  float* T1 = smx + 12544;    // 12544, t1 / t2, swizzled
  float* WK = smx + 25088;    // 12544, work region
  float* SP = smx + 37632;    // 3136, W-slice / score rows

  float* Qb = WK;              // 196*16
  float* Kb = WK + 3136;       // 196*20
  float* Vb = WK + 7056;       // 196*20
  float* WoS = WK + 10976;     // 64*17
  float* MU = WK + 12064;      // 196
  float* RS = WK + 12260;      // 196
  float* HBf = WK;             // FFN hidden, 196*32 (after attention done)

  const int b = blockIdx.x;
  const int tid = threadIdx.x;
  const size_t base = (size_t)b * 12544;

  for (int i = tid; i < 12544; i += 512) {
    int t = i >> 6, c = i & 63;
    T0[SWi(t, c)] = tokens[base + i];
  }
  __syncthreads();
  ln_stats_sw(T0, MU, RS, tid);
  __syncthreads();
  for (int i = tid; i < 12544; i += 512) {
    int t = i >> 6, c = i & 63;
    int a = SWi(t, c);
    T1[a] = (T0[a] - MU[t]) * RS[t] * ln1_g[c] + ln1_b[c];
  }
  __syncthreads();

  const int grp = tid >> 5;
  const int lane = tid & 31;

  for (int h = 0; h < 4; ++h) {
    // stage Wqkv head slice (48 rows x 64, swizzled) and Wo head slice
    for (int i = tid; i < 3072; i += 512) {
      int r = i >> 6, c = i & 63;
      int gr = ((r >> 4) << 6) + (h << 4) + (r & 15);
      SP[SWi(r, c)] = Wqkv[(gr << 6) + c];
    }
    for (int i = tid; i < 1024; i += 512) {
      int c = i >> 4, j = i & 15;
      WoS[c * 17 + j] = Wo[(c << 6) + (h << 4) + j];
    }
    __syncthreads();
    // QKV: out[t][r] = dot64(T1[t], W[r]) + bias; 2 tokens x 4 rows per tile
    for (int i = tid; i < 1176; i += 512) {
      int tp = i / 12, rq = i - tp * 12;
      float acc0[4] = {0.f, 0.f, 0.f, 0.f}, acc1[4] = {0.f, 0.f, 0.f, 0.f};
#pragma unroll
      for (int q = 0; q < 16; ++q) {
        float4 a0 = *(const float4*)&T1[SW4i(tp, q)];
        float4 a1 = *(const float4*)&T1[SW4i(tp + 98, q)];
#pragma unroll
        for (int rr = 0; rr < 4; ++rr) {
          float4 w = *(const float4*)&SP[SW4i(rq * 4 + rr, q)];
          acc0[rr] += a0.x * w.x + a0.y * w.y + a0.z * w.z + a0.w * w.w;
          acc1[rr] += a1.x * w.x + a1.y * w.y + a1.z * w.z + a1.w * w.w;
        }
      }
#pragma unroll
      for (int rr = 0; rr < 4; ++rr) {
        int r = rq * 4 + rr;
        int s = r >> 4, j = r & 15;
        float bias = bqkv[(s << 6) + (h << 4) + j];
        float v0 = acc0[rr] + bias, v1 = acc1[rr] + bias;
        if (s == 0) {
          Qb[tp * 16 + j] = v0; Qb[(tp + 98) * 16 + j] = v1;
        } else if (s == 1) {
          Kb[tp * 20 + j] = v0; Kb[(tp + 98) * 20 + j] = v1;
        } else {
          Vb[tp * 20 + j] = v0; Vb[(tp + 98) * 20 + j] = v1;
        }
      }
    }
    __syncthreads();
    // attention: each 32-lane group owns one query row per 16-row tile.
    for (int r0 = 0; r0 < 196; r0 += 16) {
      int nr = 196 - r0; if (nr > 16) nr = 16;
      int row = r0 + grp;
      float* Srow = SP + grp * 196;
      float rowmax = -1e30f;
      if (grp < nr) {
        float4 qa = *(const float4*)&Qb[row * 16];
        float4 qb = *(const float4*)&Qb[row * 16 + 4];
        float4 qc = *(const float4*)&Qb[row * 16 + 8];
        float4 qd = *(const float4*)&Qb[row * 16 + 12];
        for (int k = lane; k < 196; k += 32) {
          float4 k0 = *(const float4*)&Kb[k * 20];
          float4 k1 = *(const float4*)&Kb[k * 20 + 4];
          float4 k2 = *(const float4*)&Kb[k * 20 + 8];
          float4 k3 = *(const float4*)&Kb[k * 20 + 12];
          float d = qa.x * k0.x + qa.y * k0.y + qa.z * k0.z + qa.w * k0.w +
                    qb.x * k1.x + qb.y * k1.y + qb.z * k1.z + qb.w * k1.w +
                    qc.x * k2.x + qc.y * k2.y + qc.z * k2.z + qc.w * k2.w +
                    qd.x * k3.x + qd.y * k3.y + qd.z * k3.z + qd.w * k3.w;
          d *= 0.25f;
          Srow[k] = d;
          rowmax = fmaxf(rowmax, d);
        }
      }
#pragma unroll
      for (int m = 16; m; m >>= 1) rowmax = fmaxf(rowmax, __shfl_xor(rowmax, m, 64));
      float esum = 0.f;
      if (grp < nr) {
        for (int k = lane; k < 196; k += 32) {
          float e = __expf(Srow[k] - rowmax);
          Srow[k] = e;
          esum += e;
        }
      }
#pragma unroll
      for (int m = 16; m; m >>= 1) esum += __shfl_xor(esum, m, 64);
      const int e8 = lane & 7, cq = lane >> 3;
      float o0 = 0.f, o1 = 0.f, o2 = 0.f, o3 = 0.f;
      if (grp < nr) {
        for (int k = e8; k < 196; k += 8) {
          float pz = Srow[k];
          float4 vv = *(const float4*)&Vb[k * 20 + cq * 4];
          o0 += pz * vv.x; o1 += pz * vv.y; o2 += pz * vv.z; o3 += pz * vv.w;
        }
      }
#pragma unroll
      for (int m = 4; m; m >>= 1) {
        o0 += __shfl_xor(o0, m, 64);
        o1 += __shfl_xor(o1, m, 64);
        o2 += __shfl_xor(o2, m, 64);
        o3 += __shfl_xor(o3, m, 64);
      }
      float inv = (grp < nr) ? (1.0f / esum) : 0.f;
      o0 *= inv; o1 *= inv; o2 *= inv; o3 *= inv;
      // gather full o[16] of this row to every lane of the group (bpermute)
      float o_all[16];
      int lanebase = (tid & 32) | (tid & 7);
#pragma unroll
      for (int q4 = 0; q4 < 4; ++q4) {
        int src = lanebase | (q4 << 3);
        o_all[q4 * 4 + 0] = __shfl(o0, src, 64);
        o_all[q4 * 4 + 1] = __shfl(o1, src, 64);
        o_all[q4 * 4 + 2] = __shfl(o2, src, 64);
        o_all[q4 * 4 + 3] = __shfl(o3, src, 64);
      }
      // rank-16 Wo update of this row: lane handles c = 2*lane, 2*lane+1
      if (grp < nr) {
#pragma unroll
        for (int ci = 0; ci < 2; ++ci) {
          int c = lane * 2 + ci;
          float a2 = 0.f;
#pragma unroll
          for (int j = 0; j < 16; ++j) a2 += o_all[j] * WoS[c * 17 + j];
          T0[SWi(row, c)] += a2;
        }
      }
    }
    __syncthreads();
  }

  // + bo
  for (int i = tid; i < 12544; i += 512) {
    int t = i >> 6, c = i & 63;
    T0[SWi(t, c)] += bo[c];
  }
  __syncthreads();
  // LN2 -> t2 in T1
  ln_stats_sw(T0, MU, RS, tid);
  __syncthreads();
  for (int i = tid; i < 12544; i += 512) {
    int t = i >> 6, c = i & 63;
    int a = SWi(t, c);
    T1[a] = (T0[a] - MU[t]) * RS[t] * ln2_g[c] + ln2_b[c];
  }
  __syncthreads();
  // FFN: 8 chunks of 32 hidden
  for (int jj = 0; jj < 256; jj += 32) {
    for (int i = tid; i < 2048; i += 512) {
      int r = i >> 6, c = i & 63;
      SP[SWi(r, c)] = W1[(jj + r) * 64 + c];
    }
    __syncthreads();
    for (int i = tid; i < 784; i += 512) {
      int tp = i >> 3, rq = i & 7;
      float acc0[4] = {0.f, 0.f, 0.f, 0.f}, acc1[4] = {0.f, 0.f, 0.f, 0.f};
#pragma unroll
      for (int q = 0; q < 16; ++q) {
        float4 a0 = *(const float4*)&T1[SW4i(tp, q)];
        float4 a1 = *(const float4*)&T1[SW4i(tp + 98, q)];
#pragma unroll
        for (int rr = 0; rr < 4; ++rr) {
          float4 w = *(const float4*)&SP[SW4i(rq * 4 + rr, q)];
          acc0[rr] += a0.x * w.x + a0.y * w.y + a0.z * w.z + a0.w * w.w;
          acc1[rr] += a1.x * w.x + a1.y * w.y + a1.z * w.z + a1.w * w.w;
        }
      }
#pragma unroll
      for (int rr = 0; rr < 4; ++rr) {
        int r = rq * 4 + rr;
        float bb = b1[jj + r];
        HBf[SHi(tp, r)] = gelu_exact(acc0[rr] + bb);
        HBf[SHi(tp + 98, r)] = gelu_exact(acc1[rr] + bb);
      }
    }
    __syncthreads();
    for (int i = tid; i < 2048; i += 512) {
      int c = i >> 5, j = i & 31;
      SP[SHi(c, j)] = W2[(c << 8) + jj + j];
    }
    __syncthreads();
    for (int i = tid; i < 1568; i += 512) {
      int tp = i >> 4, cq2 = i & 15;
      float acc0[4] = {0.f, 0.f, 0.f, 0.f}, acc1[4] = {0.f, 0.f, 0.f, 0.f};
#pragma unroll
      for (int q = 0; q < 8; ++q) {
        float4 h0 = *(const float4*)&HBf[SH4i(tp, q)];
        float4 h1 = *(const float4*)&HBf[SH4i(tp + 98, q)];
#pragma unroll
        for (int ccx = 0; ccx < 4; ++ccx) {
          float4 w = *(const float4*)&SP[SH4i(cq2 * 4 + ccx, q)];
          acc0[ccx] += h0.x * w.x + h0.y * w.y + h0.z * w.z + h0.w * w.w;
          acc1[ccx] += h1.x * w.x + h1.y * w.y + h1.z * w.z + h1.w * w.w;
        }
      }
#pragma unroll
      for (int ccx = 0; ccx < 4; ++ccx) {
        T0[SWi(tp, cq2 * 4 + ccx)] += acc0[ccx];
        T0[SWi(tp + 98, cq2 * 4 + ccx)] += acc1[ccx];
      }
    }
    __syncthreads();
  }
  // + b2, final LN, write out
  for (int i = tid; i < 12544; i += 512) {
    int t = i >> 6, c = i & 63;
    T0[SWi(t, c)] += b2[c];
  }
  __syncthreads();
  ln_stats_sw(T0, MU, RS, tid);
  __syncthreads();
  for (int i = tid; i < 12544; i += 512) {
    int t = i >> 6, c = i & 63;
    float v = T0[SWi(t, c)];
    tokens[base + i] = (v - MU[t]) * RS[t] * tln_g[c] + tln_b[c];
  }
}

// ---------------------------------------------------------------------------
// Kernel C: slot attention + spmask + classifier. one block per image, 256 thr
// ---------------------------------------------------------------------------
__global__ __launch_bounds__(256) void k_slots(
    const float* __restrict__ tokens, const float* __restrict__ slot_q,
    const float* __restrict__ cls_w, const float* __restrict__ cls_b,
    const int* __restrict__ use_spmask_p, const int* __restrict__ grid_p,
    float* __restrict__ out) {
  __shared__ float TOK[12544];   // swizzled tokens
  __shared__ float Abuf[12 * 196];
  __shared__ float SQS[12 * 64]; // normalized slot_q, then S
  __shared__ float INV[196];
  __shared__ float VV[64];
  __shared__ float Pv[12];
  __shared__ float M2[12];
  __shared__ float ISN[12];
  __shared__ float ZS[2];

  const int b = blockIdx.x;
  const int tid = threadIdx.x;
  const size_t base = (size_t)b * 12544;
  (void)grid_p;

  for (int i = tid; i < 12544; i += 256) {
    int t = i >> 6, c = i & 63;
    TOK[SWi(t, c)] = tokens[base + i];
  }
  __syncthreads();
  if (tid < 196) {
    float ss = 0.f;
#pragma unroll
    for (int q = 0; q < 16; ++q) {
      float4 v = *(const float4*)&TOK[SW4i(tid, q)];
      ss += v.x * v.x + v.y * v.y + v.z * v.z + v.w * v.w;
    }
    INV[tid] = 1.0f / fmaxf(sqrtf(ss), 1e-12f);
  }
  if (tid < 192) {
    int m = tid >> 4, l = tid & 15;
    float ss = 0.f;
#pragma unroll
    for (int c = l; c < 64; c += 16) {
      float v = slot_q[m * 64 + c];
      ss += v * v;
    }
#pragma unroll
    for (int mm = 8; mm; mm >>= 1) ss += __shfl_xor(ss, mm, 64);
    float invq = 1.0f / fmaxf(sqrtf(ss), 1e-12f);
#pragma unroll
    for (int c = l; c < 64; c += 16) SQS[m * 64 + c] = slot_q[m * 64 + c] * invq;
  }
  __syncthreads();
  // A logits
  for (int i = tid; i < 2352; i += 256) {
    int m = i / 196, n = i - m * 196;
    float d = 0.f;
#pragma unroll
    for (int q = 0; q < 16; ++q) {
      float4 tv = *(const float4*)&TOK[SW4i(n, q)];
      float4 sv = *(const float4*)&SQS[m * 64 + q * 4];
      d += tv.x * sv.x + tv.y * sv.y + tv.z * sv.z + tv.w * sv.w;
    }
    Abuf[i] = d * INV[n] * 0.125f;
  }
  __syncthreads();
  const int use_spmask = *use_spmask_p;
  if (tid < 192) {
    int m = tid >> 4, l = tid & 15;
    float* Am = Abuf + m * 196;
    float mx = -1e30f;
    for (int n = l; n < 196; n += 16) mx = fmaxf(mx, Am[n]);
#pragma unroll
    for (int mm = 8; mm; mm >>= 1) mx = fmaxf(mx, __shfl_xor(mx, mm, 64));
    float se = 0.f, mc0 = 0.f, mc1 = 0.f, mc2 = 0.f, mc3 = 0.f;
    for (int n = l; n < 196; n += 16) {
      float e = __expf(Am[n] - mx);
      Am[n] = e;
      se += e;
      int yy = n / 14, xx = n - yy * 14;
      int cell = ((yy >= 7) ? 2 : 0) + ((xx >= 7) ? 1 : 0);
      mc0 += (cell == 0) ? e : 0.f;
      mc1 += (cell == 1) ? e : 0.f;
      mc2 += (cell == 2) ? e : 0.f;
      mc3 += (cell == 3) ? e : 0.f;
    }
#pragma unroll
    for (int mm = 8; mm; mm >>= 1) {
      se += __shfl_xor(se, mm, 64);
      mc0 += __shfl_xor(mc0, mm, 64);
      mc1 += __shfl_xor(mc1, mm, 64);
      mc2 += __shfl_xor(mc2, mm, 64);
      mc3 += __shfl_xor(mc3, mm, 64);
    }
    float invse = 1.0f / se;
    if (use_spmask) {
      // top-2 cells, strict > so ties pick lower index (lax.top_k order)
      int g1 = 0; float bv1 = mc0;
      if (mc1 > bv1) { bv1 = mc1; g1 = 1; }
      if (mc2 > bv1) { bv1 = mc2; g1 = 2; }
      if (mc3 > bv1) { bv1 = mc3; g1 = 3; }
      int g2 = -1; float bv2 = -1e30f;
      if (g1 != 0 && mc0 > bv2) { bv2 = mc0; g2 = 0; }
      if (g1 != 1 && mc1 > bv2) { bv2 = mc1; g2 = 1; }
      if (g1 != 2 && mc2 > bv2) { bv2 = mc2; g2 = 2; }
      if (g1 != 3 && mc3 > bv2) { bv2 = mc3; g2 = 3; }
      float sacc = 0.f;
      for (int n = l; n < 196; n += 16) {
        float a = Am[n] * invse;  // normalized A_slot
        Am[n] = a;
        int yy = n / 14, xx = n - yy * 14;
        int cell = ((yy >= 7) ? 2 : 0) + ((xx >= 7) ? 1 : 0);
        sacc += (cell == g1 || cell == g2) ? a : 0.f;
      }
#pragma unroll
      for (int mm = 8; mm; mm >>= 1) sacc += __shfl_xor(sacc, mm, 64);
      float invs = 1.0f / fmaxf(sacc, 1e-8f);
      float m2acc = 0.f;
      for (int n = l; n < 196; n += 16) {
        int yy = n / 14, xx = n - yy * 14;
        int cell = ((yy >= 7) ? 2 : 0) + ((xx >= 7) ? 1 : 0);
        float a = (cell == g1 || cell == g2) ? (Am[n] * invs) : 0.f;
        Am[n] = a;  // A_eff
        m2acc += a;
      }
#pragma unroll
      for (int mm = 8; mm; mm >>= 1) m2acc += __shfl_xor(m2acc, mm, 64);
      if (l == 0) M2[m] = m2acc;
    } else {
      for (int n = l; n < 196; n += 16) Am[n] *= invse;
      if (l == 0) M2[m] = mx + logf(se);  // lse
    }
  }
  __syncthreads();
  if (tid == 0) {
    float mean = 0.f;
    for (int m = 0; m < 12; ++m) mean += M2[m];
    mean *= (1.0f / 12.0f);
    float zmax = -1e30f;
    for (int m = 0; m < 12; ++m) {
      float z = (M2[m] - mean) * 2.0f;  // / tau_p (0.5)
      Pv[m] = z;
      zmax = fmaxf(zmax, z);
    }
    float seP = 0.f;
    for (int m = 0; m < 12; ++m) {
      float e = __expf(Pv[m] - zmax);
      Pv[m] = e;
      seP += e;
    }
    float invP = 1.0f / seP;
    float sump = 0.f;
    for (int m = 0; m < 12; ++m) {
      float p = Pv[m] * invP;
      Pv[m] = p;
      sump += p;
    }
    ZS[0] = sump;
  }
  __syncthreads();
  // S[m][c] = sum_n A_eff[m][n] * TOK[n][c]  (into SQS, slot_q no longer used)
  for (int i = tid; i < 768; i += 256) {
    int m = i >> 6, c = i & 63;
    float a2 = 0.f;
    const float* Am = Abuf + m * 196;
    for (int n = 0; n < 196; ++n) a2 += Am[n] * TOK[SWi(n, c)];
    SQS[m * 64 + c] = a2;
  }
  __syncthreads();
  if (tid < 192) {
    int m = tid >> 4, l = tid & 15;
    float ss = 0.f;
#pragma unroll
    for (int c = l; c < 64; c += 16) {
      float v = SQS[m * 64 + c];
      ss += v * v;
    }
#pragma unroll
    for (int mm = 8; mm; mm >>= 1) ss += __shfl_xor(ss, mm, 64);
    if (l == 0) ISN[m] = 1.0f / fmaxf(sqrtf(ss), 1e-12f);
  }
  __syncthreads();
  if (tid < 64) {
    float v = 0.f;
#pragma unroll
    for (int m = 0; m < 12; ++m) v += Pv[m] * ISN[m] * SQS[m * 64 + tid];
    VV[tid] = v;
  }
  __syncthreads();
  if (tid < 47) {
    float a2 = 0.f;
#pragma unroll
    for (int q = 0; q < 16; ++q) {
      float4 w = *(const float4*)&cls_w[tid * 64 + q * 4];
      float4 v = *(const float4*)&VV[q * 4];
      a2 += w.x * v.x + w.y * v.y + w.z * v.z + w.w * v.w;
    }
    out[(size_t)b * 47 + tid] = a2 + cls_b[tid] * ZS[0];
  }
}

// ---------------------------------------------------------------------------
extern "C" void kernel_launch(void* const* d_in, const int* in_sizes, int n_in,
                              void* d_out, int out_size, void* d_ws, size_t ws_size,
                              hipStream_t stream) {
  (void)n_in; (void)out_size; (void)ws_size;
  const float* x      = (const float*)d_in[0];
  const float* conv_w = (const float*)d_in[1];
  const float* proj_w = (const float*)d_in[2];
  const float* proj_b = (const float*)d_in[3];
  const float* ln1_g  = (const float*)d_in[4];
  const float* ln1_b  = (const float*)d_in[5];
  const float* Wqkv   = (const float*)d_in[6];
  const float* bqkv   = (const float*)d_in[7];
  const float* Wo     = (const float*)d_in[8];
  const float* bo     = (const float*)d_in[9];
  const float* ln2_g  = (const float*)d_in[10];
  const float* ln2_b  = (const float*)d_in[11];
  const float* W1     = (const float*)d_in[12];
  const float* b1     = (const float*)d_in[13];
  const float* W2     = (const float*)d_in[14];
  const float* b2     = (const float*)d_in[15];
  const float* tln_g  = (const float*)d_in[16];
  const float* tln_b  = (const float*)d_in[17];
  const float* slot_q = (const float*)d_in[18];
  const float* cls_w  = (const float*)d_in[19];
  const float* cls_b  = (const float*)d_in[20];
  const int* use_spm  = (const int*)d_in[21];
  const int* spgrid   = (const int*)d_in[22];

  const int B = in_sizes[0] / 784;
  float* tokens = (float*)d_ws;  // B x 196 x 64 f32

  k_conv_proj<<<B, 256, 0, stream>>>(x, conv_w, proj_w, proj_b, tokens);

  const size_t shb = 40768 * sizeof(float);  // 163,072 B (<= 160 KiB LDS)
  (void)hipFuncSetAttribute((const void*)k_xformer,
                            hipFuncAttributeMaxDynamicSharedMemorySize, (int)shb);
  k_xformer<<<B, 512, shb, stream>>>(tokens, ln1_g, ln1_b, Wqkv, bqkv, Wo, bo,
                                     ln2_g, ln2_b, W1, b1, W2, b2, tln_g, tln_b);

  k_slots<<<B, 256, 0, stream>>>(tokens, slot_q, cls_w, cls_b, use_spm, spgrid,
                                 (float*)d_out);
}

// Round 2
// 1310.412 us; speedup vs baseline: 5.8754x; 5.8754x over previous
//
#include <hip/hip_runtime.h>
#include <math.h>

// ---------------------------------------------------------------------------
// SlotClassifier: conv (f32) -> transformer via f16 MFMA -> slots (f32)
// tokens buffer (B x 196 x 64 f32) lives in d_ws.
// ---------------------------------------------------------------------------

typedef _Float16 half_t;
typedef __attribute__((ext_vector_type(4))) _Float16 half4;
typedef __attribute__((ext_vector_type(2))) _Float16 half2t;
typedef __attribute__((ext_vector_type(4))) float f32x4;

__device__ __forceinline__ f32x4 MFMA16(half4 a, half4 b, f32x4 c) {
  return __builtin_amdgcn_mfma_f32_16x16x16f16(a, b, c, 0, 0, 0);
}

// XOR swizzle for 64-float rows: quad index ^= (row & 15).
__device__ __forceinline__ int SWi(int row, int col) {
  return (row << 6) | (((((col >> 2) ^ row) & 15)) << 2) | (col & 3);
}
__device__ __forceinline__ int SW4i(int row, int q) {
  return (row << 6) | ((((q ^ row) & 15)) << 2);
}
// f16 rows of 64: unit = 4 f16 (8B), 16 units, unit ^= row&15.
__device__ __forceinline__ int XH(int t, int k) {
  return (t << 6) | (((((k >> 2) ^ t) & 15)) << 2) | (k & 3);
}
__device__ __forceinline__ int XH4(int t, int k4) {
  return (t << 6) | ((((k4 ^ t) & 15)) << 2);
}
__device__ __forceinline__ int KBI(int h, int n, int d) {
  return (h * 208 + n) * 20 + d;
}
__device__ __forceinline__ int VTI(int h, int d, int n) {
  return (h * 16 + d) * 212 + n;
}

__device__ __forceinline__ float gelu_exact(float v) {
  return 0.5f * v * (1.0f + erff(v * 0.7071067811865476f));
}

// ---------------------------------------------------------------------------
// Kernel A: conv1 (1->150, k9 s2 p4) + exact gelu + 1x1 proj to 64  (f32)
// ---------------------------------------------------------------------------
__global__ __launch_bounds__(256) void k_conv_proj(
    const float* __restrict__ x, const float* __restrict__ conv_w,
    const float* __restrict__ proj_w, const float* __restrict__ proj_b,
    float* __restrict__ tokens) {
  __shared__ float xs[784];
  __shared__ float wsT[81 * 32];
  __shared__ float hb[196 * 36];
  __shared__ float pw[32 * 65];

  const int b = blockIdx.x;
  const int tid = threadIdx.x;

  for (int i = tid; i < 784; i += 256) xs[i] = x[b * 784 + i];

  const int dc0 = (tid & 31) * 2;
  const int t0 = tid >> 5;
  float acc[25][2];
#pragma unroll
  for (int j = 0; j < 25; ++j) { acc[j][0] = 0.f; acc[j][1] = 0.f; }

  const int cq = tid & 7;
  const int pxg = tid >> 3;

  for (int cc = 0; cc < 160; cc += 32) {
    __syncthreads();
    for (int i = tid; i < 81 * 32; i += 256) {
      int ch = i & 31, tap = i >> 5;
      int gch = cc + ch;
      wsT[tap * 32 + ch] = (gch < 150) ? conv_w[gch * 81 + tap] : 0.f;
    }
    for (int i = tid; i < 2048; i += 256) {
      int ch = i & 31, d = i >> 5;
      int gch = cc + ch;
      pw[ch * 65 + d] = (gch < 150) ? proj_w[d * 150 + gch] : 0.f;
    }
    __syncthreads();
    for (int pp = 0; pp < 4; ++pp) {
      int p = pxg + 32 * pp;
      if (p < 98) {
        int px0 = 2 * p, px1 = 2 * p + 1;
        int oy0 = px0 / 14, ox0 = px0 - oy0 * 14;
        int oy1 = px1 / 14, ox1 = px1 - oy1 * 14;
        int iy0 = oy0 * 2 - 4, ix0 = ox0 * 2 - 4;
        int iy1 = oy1 * 2 - 4, ix1 = ox1 * 2 - 4;
        float a00 = 0.f, a01 = 0.f, a02 = 0.f, a03 = 0.f;
        float a10 = 0.f, a11 = 0.f, a12 = 0.f, a13 = 0.f;
        for (int ky = 0; ky < 9; ++ky) {
          int y0 = iy0 + ky, y1 = iy1 + ky;
          bool vy0 = (unsigned)y0 < 28u, vy1 = (unsigned)y1 < 28u;
          if (!vy0 && !vy1) continue;
#pragma unroll
          for (int kx = 0; kx < 9; ++kx) {
            float4 w = *(const float4*)&wsT[(ky * 9 + kx) * 32 + cq * 4];
            int x0i = ix0 + kx, x1i = ix1 + kx;
            if (vy0 && (unsigned)x0i < 28u) {
              float xv = xs[y0 * 28 + x0i];
              a00 += xv * w.x; a01 += xv * w.y; a02 += xv * w.z; a03 += xv * w.w;
            }
            if (vy1 && (unsigned)x1i < 28u) {
              float xv = xs[y1 * 28 + x1i];
              a10 += xv * w.x; a11 += xv * w.y; a12 += xv * w.z; a13 += xv * w.w;
            }
          }
        }
        int hb0 = px0 * 36 + cq * 4;
        hb[hb0 + 0] = gelu_exact(a00); hb[hb0 + 1] = gelu_exact(a01);
        hb[hb0 + 2] = gelu_exact(a02); hb[hb0 + 3] = gelu_exact(a03);
        int hb1 = px1 * 36 + cq * 4;
        hb[hb1 + 0] = gelu_exact(a10); hb[hb1 + 1] = gelu_exact(a11);
        hb[hb1 + 2] = gelu_exact(a12); hb[hb1 + 3] = gelu_exact(a13);
      }
    }
    __syncthreads();
    for (int cv = 0; cv < 8; ++cv) {
      float w00 = pw[(cv * 4 + 0) * 65 + dc0], w01 = pw[(cv * 4 + 0) * 65 + dc0 + 1];
      float w10 = pw[(cv * 4 + 1) * 65 + dc0], w11 = pw[(cv * 4 + 1) * 65 + dc0 + 1];
      float w20 = pw[(cv * 4 + 2) * 65 + dc0], w21 = pw[(cv * 4 + 2) * 65 + dc0 + 1];
      float w30 = pw[(cv * 4 + 3) * 65 + dc0], w31 = pw[(cv * 4 + 3) * 65 + dc0 + 1];
#pragma unroll
      for (int j = 0; j < 25; ++j) {
        int t = t0 + 8 * j;
        if (t < 196) {
          float4 hq = *(const float4*)&hb[t * 36 + cv * 4];
          acc[j][0] += hq.x * w00 + hq.y * w10 + hq.z * w20 + hq.w * w30;
          acc[j][1] += hq.x * w01 + hq.y * w11 + hq.z * w21 + hq.w * w31;
        }
      }
    }
  }
  float pb0 = proj_b[dc0], pb1 = proj_b[dc0 + 1];
#pragma unroll
  for (int j = 0; j < 25; ++j) {
    int t = t0 + 8 * j;
    if (t < 196) {
      size_t o = (size_t)b * 12544 + (size_t)t * 64 + dc0;
      tokens[o] = acc[j][0] + pb0;
      tokens[o + 1] = acc[j][1] + pb1;
    }
  }
}

// ---------------------------------------------------------------------------
// Kernel B: transformer encoder layer + final LN, f16 MFMA trunk
// one block per image, 512 threads (8 waves), 138,784 B dynamic LDS
// LDS words: T0[0,12544) Xh[12544,19200) Kb[19200,27520) VT[27520,34304)
//            MU[34304..] RS[34500..]  (Hb aliases Kb; W1c/W2c alias VT)
// ---------------------------------------------------------------------------
__device__ __forceinline__ void ln_stats_sw(const float* __restrict__ buf,
                                            float* __restrict__ MU,
                                            float* __restrict__ RS, int tid) {
  if (tid < 196) {
    float s = 0.f;
#pragma unroll
    for (int q = 0; q < 16; ++q) {
      float4 v = *(const float4*)&buf[SW4i(tid, q)];
      s += v.x + v.y + v.z + v.w;
    }
    float mu = s * 0.015625f;
    float vs = 0.f;
#pragma unroll
    for (int q = 0; q < 16; ++q) {
      float4 v = *(const float4*)&buf[SW4i(tid, q)];
      float a = v.x - mu, b = v.y - mu, c = v.z - mu, d = v.w - mu;
      vs += a * a + b * b + c * c + d * d;
    }
    MU[tid] = mu;
    RS[tid] = rsqrtf(vs * 0.015625f + 1e-5f);
  }
}

__global__ __launch_bounds__(512, 1) void k_xformer(
    float* __restrict__ tokens,
    const float* __restrict__ ln1_g, const float* __restrict__ ln1_b,
    const float* __restrict__ Wqkv, const float* __restrict__ bqkv,
    const float* __restrict__ Wo, const float* __restrict__ bo,
    const float* __restrict__ ln2_g, const float* __restrict__ ln2_b,
    const float* __restrict__ W1, const float* __restrict__ b1,
    const float* __restrict__ W2, const float* __restrict__ b2,
    const float* __restrict__ tln_g, const float* __restrict__ tln_b) {
  extern __shared__ float smx[];
  float* T0 = smx;
  half_t* Xh = (half_t*)(smx + 12544);
  half_t* Kb = (half_t*)(smx + 19200);
  half_t* VT = (half_t*)(smx + 27520);
  float* MU = smx + 34304;
  float* RS = smx + 34500;
  half_t* Hb = (half_t*)(smx + 19200);   // alias Kb (FFN phase)
  half_t* W1c = (half_t*)(smx + 27520);  // alias VT
  half_t* W2c = (half_t*)(smx + 29568);  // alias VT + 2048 words

  const int b = blockIdx.x;
  const int tid = threadIdx.x;
  const size_t base = (size_t)b * 12544;
  const int wv = tid >> 6, ln = tid & 63, g = ln >> 4, li = ln & 15;

  // ---- load tokens, zero VT and Xh pad rows ----
  for (int i = tid; i < 12544; i += 512) {
    int t = i >> 6, c = i & 63;
    T0[SWi(t, c)] = tokens[base + i];
  }
  for (int i = tid; i < 6784; i += 512) smx[27520 + i] = 0.f;  // VT = 0
  for (int i = tid; i < 384; i += 512) smx[12544 + 6272 + i] = 0.f;  // Xh pads
  __syncthreads();
  ln_stats_sw(T0, MU, RS, tid);
  __syncthreads();
  // t1 -> Xh (f16, swizzled)
  for (int i = tid; i < 6272; i += 512) {
    int t = i >> 5, c0 = (i & 31) * 2;
    float mu = MU[t], rs = RS[t];
    float v0 = (T0[SWi(t, c0)] - mu) * rs * ln1_g[c0] + ln1_b[c0];
    float v1 = (T0[SWi(t, c0 + 1)] - mu) * rs * ln1_g[c0 + 1] + ln1_b[c0 + 1];
    *(half2t*)&Xh[XH(t, c0)] = half2t{(half_t)v0, (half_t)v1};
  }
  __syncthreads();

  // ---- QKV^T GEMM: wave wv computes r-tile 4+wv (K head wv / V^T head wv-4)
  {
    const int r0 = 64 + wv * 16;
    half4 af[4];
#pragma unroll
    for (int ks = 0; ks < 4; ++ks) {
      const float* wp = &Wqkv[(r0 + li) * 64 + ks * 16 + g * 4];
      af[ks] = half4{(half_t)wp[0], (half_t)wp[1], (half_t)wp[2], (half_t)wp[3]};
    }
    float bias[4];
#pragma unroll
    for (int r = 0; r < 4; ++r) bias[r] = bqkv[r0 + g * 4 + r];
    for (int tt = 0; tt < 13; ++tt) {
      int trow = tt * 16 + li;
      f32x4 acc = {0.f, 0.f, 0.f, 0.f};
#pragma unroll
      for (int ks = 0; ks < 4; ++ks) {
        half4 bf = *(const half4*)&Xh[XH4(trow, ks * 4 + g)];
        acc = MFMA16(af[ks], bf, acc);
      }
      if (wv < 4) {
#pragma unroll
        for (int r = 0; r < 4; ++r)
          Kb[KBI(wv, trow, g * 4 + r)] = (half_t)(acc[r] + bias[r]);
      } else {
#pragma unroll
        for (int r = 0; r < 4; ++r)
          VT[VTI(wv - 4, g * 4 + r, trow)] = (half_t)(acc[r] + bias[r]);
      }
    }
  }
  // ---- Q part: wave's own q-tiles (qt = wv, wv+8), kept in registers
  half4 qf[2][4];
#pragma unroll
  for (int qi = 0; qi < 2; ++qi) {
    int qt = wv + 8 * qi;
    if (qt < 13) {
#pragma unroll
      for (int h = 0; h < 4; ++h) {
        f32x4 acc = {0.f, 0.f, 0.f, 0.f};
#pragma unroll
        for (int ks = 0; ks < 4; ++ks) {
          const float* wp = &Wqkv[(h * 16 + li) * 64 + ks * 16 + g * 4];
          half4 a = half4{(half_t)wp[0], (half_t)wp[1], (half_t)wp[2], (half_t)wp[3]};
          half4 bf = *(const half4*)&Xh[XH4(qt * 16 + li, ks * 4 + g)];
          acc = MFMA16(a, bf, acc);
        }
#pragma unroll
        for (int r = 0; r < 4; ++r)
          qf[qi][h][r] = (half_t)((acc[r] + bqkv[h * 16 + g * 4 + r]) * 0.25f);
      }
    }
  }
  __syncthreads();

  // ---- attention: per owned q-tile, chained MFMAs, softmax in-register ----
#pragma unroll
  for (int qi = 0; qi < 2; ++qi) {
    int qt = wv + 8 * qi;
    if (qt < 13) {
      f32x4 z[4] = {{0.f,0.f,0.f,0.f},{0.f,0.f,0.f,0.f},{0.f,0.f,0.f,0.f},{0.f,0.f,0.f,0.f}};
#pragma unroll
      for (int h = 0; h < 4; ++h) {
        f32x4 s[13];
#pragma unroll
        for (int nt = 0; nt < 13; ++nt) {
          half4 ka = *(const half4*)&Kb[KBI(h, nt * 16 + li, g * 4)];
          f32x4 zz = {0.f, 0.f, 0.f, 0.f};
          s[nt] = MFMA16(ka, qf[qi][h], zz);
        }
        if (g > 0) { s[12][0] = -1e30f; s[12][1] = -1e30f; s[12][2] = -1e30f; s[12][3] = -1e30f; }
        float m = -1e30f;
#pragma unroll
        for (int nt = 0; nt < 13; ++nt) {
#pragma unroll
          for (int r = 0; r < 4; ++r) m = fmaxf(m, s[nt][r]);
        }
        m = fmaxf(m, __shfl_xor(m, 16, 64));
        m = fmaxf(m, __shfl_xor(m, 32, 64));
        float es = 0.f;
        half4 p[13];
#pragma unroll
        for (int nt = 0; nt < 13; ++nt) {
#pragma unroll
          for (int r = 0; r < 4; ++r) {
            float e = __expf(s[nt][r] - m);
            es += e;
            p[nt][r] = (half_t)e;
          }
        }
        es += __shfl_xor(es, 16, 64);
        es += __shfl_xor(es, 32, 64);
        f32x4 oa = {0.f, 0.f, 0.f, 0.f}, ob = {0.f, 0.f, 0.f, 0.f};
#pragma unroll
        for (int nt = 0; nt < 13; nt += 2) {
          half4 va = *(const half4*)&VT[VTI(h, li, nt * 16 + g * 4)];
          oa = MFMA16(va, p[nt], oa);
        }
#pragma unroll
        for (int nt = 1; nt < 13; nt += 2) {
          half4 va = *(const half4*)&VT[VTI(h, li, nt * 16 + g * 4)];
          ob = MFMA16(va, p[nt], ob);
        }
        float inv = 1.0f / es;
        half4 of;
#pragma unroll
        for (int r = 0; r < 4; ++r) of[r] = (half_t)((oa[r] + ob[r]) * inv);
#pragma unroll
        for (int ct = 0; ct < 4; ++ct) {
          const float* wp = &Wo[(ct * 16 + li) * 64 + h * 16 + g * 4];
          half4 wa = half4{(half_t)wp[0], (half_t)wp[1], (half_t)wp[2], (half_t)wp[3]};
          z[ct] = MFMA16(wa, of, z[ct]);
        }
      }
      int q = qt * 16 + li;
      if (q < 196) {
#pragma unroll
        for (int ct = 0; ct < 4; ++ct) {
#pragma unroll
          for (int r = 0; r < 4; ++r) T0[SWi(q, ct * 16 + g * 4 + r)] += z[ct][r];
        }
      }
    }
  }
  __syncthreads();

  // ---- + bo, LN2 -> t2 in Xh ----
  for (int i = tid; i < 12544; i += 512) {
    int t = i >> 6, c = i & 63;
    T0[SWi(t, c)] += bo[c];
  }
  __syncthreads();
  ln_stats_sw(T0, MU, RS, tid);
  __syncthreads();
  for (int i = tid; i < 6272; i += 512) {
    int t = i >> 5, c0 = (i & 31) * 2;
    float mu = MU[t], rs = RS[t];
    float v0 = (T0[SWi(t, c0)] - mu) * rs * ln2_g[c0] + ln2_b[c0];
    float v1 = (T0[SWi(t, c0 + 1)] - mu) * rs * ln2_g[c0 + 1] + ln2_b[c0 + 1];
    *(half2t*)&Xh[XH(t, c0)] = half2t{(half_t)v0, (half_t)v1};
  }
  __syncthreads();

  // ---- FFN: 4 chunks of 64 hidden; acc persists in regs ----
  f32x4 facc[7] = {{0.f,0.f,0.f,0.f},{0.f,0.f,0.f,0.f},{0.f,0.f,0.f,0.f},{0.f,0.f,0.f,0.f},
                   {0.f,0.f,0.f,0.f},{0.f,0.f,0.f,0.f},{0.f,0.f,0.f,0.f}};
  for (int ch = 0; ch < 4; ++ch) {
    // stage W1 chunk rows [64][64], W2 chunk cols [64][64] as f16 swizzled
    for (int i = tid; i < 2048; i += 512) {
      int r = i >> 5, c0 = (i & 31) * 2;
      const float* wp = &W1[(ch * 64 + r) * 64 + c0];
      *(half2t*)&W1c[XH(r, c0) & 4095] = half2t{(half_t)wp[0], (half_t)wp[1]};
    }
    for (int i = tid; i < 2048; i += 512) {
      int r = i >> 5, c0 = (i & 31) * 2;
      const float* wp = &W2[r * 256 + ch * 64 + c0];
      *(half2t*)&W2c[XH(r, c0) & 4095] = half2t{(half_t)wp[0], (half_t)wp[1]};
    }
    __syncthreads();
    // H = gelu(t2 @ W1c^T + b1) -> Hb
#pragma unroll
    for (int j = 0; j < 7; ++j) {
      int u = wv + 8 * j;
      if (u < 52) {
        int mt = u >> 2, nt = u & 3;
        f32x4 acc = {0.f, 0.f, 0.f, 0.f};
#pragma unroll
        for (int ks = 0; ks < 4; ++ks) {
          half4 a = *(const half4*)&Xh[XH4(mt * 16 + li, ks * 4 + g)];
          half4 bf = *(const half4*)&W1c[XH4(nt * 16 + li, ks * 4 + g) & 4095];
          acc = MFMA16(a, bf, acc);
        }
        float bb = b1[ch * 64 + nt * 16 + li];
#pragma unroll
        for (int r = 0; r < 4; ++r)
          Hb[XH(mt * 16 + g * 4 + r, nt * 16 + li)] = (half_t)gelu_exact(acc[r] + bb);
      }
    }
    __syncthreads();
    // O2 += Hgelu @ W2c^T
#pragma unroll
    for (int j = 0; j < 7; ++j) {
      int u = wv + 8 * j;
      if (u < 52) {
        int mt = u >> 2, nt = u & 3;
#pragma unroll
        for (int ks = 0; ks < 4; ++ks) {
          half4 a = *(const half4*)&Hb[XH4(mt * 16 + li, ks * 4 + g)];
          half4 bf = *(const half4*)&W2c[XH4(nt * 16 + li, ks * 4 + g) & 4095];
          facc[j] = MFMA16(a, bf, facc[j]);
        }
      }
    }
    __syncthreads();
  }
  // write back FFN + b2 into T0
#pragma unroll
  for (int j = 0; j < 7; ++j) {
    int u = wv + 8 * j;
    if (u < 52) {
      int mt = u >> 2, nt = u & 3;
      int c = nt * 16 + li;
      float bb = b2[c];
#pragma unroll
      for (int r = 0; r < 4; ++r) {
        int t = mt * 16 + g * 4 + r;
        if (t < 196) T0[SWi(t, c)] += facc[j][r] + bb;
      }
    }
  }
  __syncthreads();
  ln_stats_sw(T0, MU, RS, tid);
  __syncthreads();
  for (int i = tid; i < 3136; i += 512) {
    int t = i >> 4, c0 = (i & 15) * 4;
    float4 v = *(const float4*)&T0[SW4i(t, c0 >> 2)];
    float mu = MU[t], rs = RS[t];
    float4 o;
    o.x = (v.x - mu) * rs * tln_g[c0] + tln_b[c0];
    o.y = (v.y - mu) * rs * tln_g[c0 + 1] + tln_b[c0 + 1];
    o.z = (v.z - mu) * rs * tln_g[c0 + 2] + tln_b[c0 + 2];
    o.w = (v.w - mu) * rs * tln_g[c0 + 3] + tln_b[c0 + 3];
    *(float4*)&tokens[base + t * 64 + c0] = o;
  }
}

// ---------------------------------------------------------------------------
// Kernel C: slot attention + spmask + classifier (f32, unchanged)
// ---------------------------------------------------------------------------
__global__ __launch_bounds__(256) void k_slots(
    const float* __restrict__ tokens, const float* __restrict__ slot_q,
    const float* __restrict__ cls_w, const float* __restrict__ cls_b,
    const int* __restrict__ use_spmask_p, const int* __restrict__ grid_p,
    float* __restrict__ out) {
  __shared__ float TOK[12544];
  __shared__ float Abuf[12 * 196];
  __shared__ float SQS[12 * 64];
  __shared__ float INV[196];
  __shared__ float VV[64];
  __shared__ float Pv[12];
  __shared__ float M2[12];
  __shared__ float ISN[12];
  __shared__ float ZS[2];

  const int b = blockIdx.x;
  const int tid = threadIdx.x;
  const size_t base = (size_t)b * 12544;
  (void)grid_p;

  for (int i = tid; i < 12544; i += 256) {
    int t = i >> 6, c = i & 63;
    TOK[SWi(t, c)] = tokens[base + i];
  }
  __syncthreads();
  if (tid < 196) {
    float ss = 0.f;
#pragma unroll
    for (int q = 0; q < 16; ++q) {
      float4 v = *(const float4*)&TOK[SW4i(tid, q)];
      ss += v.x * v.x + v.y * v.y + v.z * v.z + v.w * v.w;
    }
    INV[tid] = 1.0f / fmaxf(sqrtf(ss), 1e-12f);
  }
  if (tid < 192) {
    int m = tid >> 4, l = tid & 15;
    float ss = 0.f;
#pragma unroll
    for (int c = l; c < 64; c += 16) {
      float v = slot_q[m * 64 + c];
      ss += v * v;
    }
#pragma unroll
    for (int mm = 8; mm; mm >>= 1) ss += __shfl_xor(ss, mm, 64);
    float invq = 1.0f / fmaxf(sqrtf(ss), 1e-12f);
#pragma unroll
    for (int c = l; c < 64; c += 16) SQS[m * 64 + c] = slot_q[m * 64 + c] * invq;
  }
  __syncthreads();
  for (int i = tid; i < 2352; i += 256) {
    int m = i / 196, n = i - m * 196;
    float d = 0.f;
#pragma unroll
    for (int q = 0; q < 16; ++q) {
      float4 tv = *(const float4*)&TOK[SW4i(n, q)];
      float4 sv = *(const float4*)&SQS[m * 64 + q * 4];
      d += tv.x * sv.x + tv.y * sv.y + tv.z * sv.z + tv.w * sv.w;
    }
    Abuf[i] = d * INV[n] * 0.125f;
  }
  __syncthreads();
  const int use_spmask = *use_spmask_p;
  if (tid < 192) {
    int m = tid >> 4, l = tid & 15;
    float* Am = Abuf + m * 196;
    float mx = -1e30f;
    for (int n = l; n < 196; n += 16) mx = fmaxf(mx, Am[n]);
#pragma unroll
    for (int mm = 8; mm; mm >>= 1) mx = fmaxf(mx, __shfl_xor(mx, mm, 64));
    float se = 0.f, mc0 = 0.f, mc1 = 0.f, mc2 = 0.f, mc3 = 0.f;
    for (int n = l; n < 196; n += 16) {
      float e = __expf(Am[n] - mx);
      Am[n] = e;
      se += e;
      int yy = n / 14, xx = n - yy * 14;
      int cell = ((yy >= 7) ? 2 : 0) + ((xx >= 7) ? 1 : 0);
      mc0 += (cell == 0) ? e : 0.f;
      mc1 += (cell == 1) ? e : 0.f;
      mc2 += (cell == 2) ? e : 0.f;
      mc3 += (cell == 3) ? e : 0.f;
    }
#pragma unroll
    for (int mm = 8; mm; mm >>= 1) {
      se += __shfl_xor(se, mm, 64);
      mc0 += __shfl_xor(mc0, mm, 64);
      mc1 += __shfl_xor(mc1, mm, 64);
      mc2 += __shfl_xor(mc2, mm, 64);
      mc3 += __shfl_xor(mc3, mm, 64);
    }
    float invse = 1.0f / se;
    if (use_spmask) {
      int g1 = 0; float bv1 = mc0;
      if (mc1 > bv1) { bv1 = mc1; g1 = 1; }
      if (mc2 > bv1) { bv1 = mc2; g1 = 2; }
      if (mc3 > bv1) { bv1 = mc3; g1 = 3; }
      int g2 = -1; float bv2 = -1e30f;
      if (g1 != 0 && mc0 > bv2) { bv2 = mc0; g2 = 0; }
      if (g1 != 1 && mc1 > bv2) { bv2 = mc1; g2 = 1; }
      if (g1 != 2 && mc2 > bv2) { bv2 = mc2; g2 = 2; }
      if (g1 != 3 && mc3 > bv2) { bv2 = mc3; g2 = 3; }
      float sacc = 0.f;
      for (int n = l; n < 196; n += 16) {
        float a = Am[n] * invse;
        Am[n] = a;
        int yy = n / 14, xx = n - yy * 14;
        int cell = ((yy >= 7) ? 2 : 0) + ((xx >= 7) ? 1 : 0);
        sacc += (cell == g1 || cell == g2) ? a : 0.f;
      }
#pragma unroll
      for (int mm = 8; mm; mm >>= 1) sacc += __shfl_xor(sacc, mm, 64);
      float invs = 1.0f / fmaxf(sacc, 1e-8f);
      float m2acc = 0.f;
      for (int n = l; n < 196; n += 16) {
        int yy = n / 14, xx = n - yy * 14;
        int cell = ((yy >= 7) ? 2 : 0) + ((xx >= 7) ? 1 : 0);
        float a = (cell == g1 || cell == g2) ? (Am[n] * invs) : 0.f;
        Am[n] = a;
        m2acc += a;
      }
#pragma unroll
      for (int mm = 8; mm; mm >>= 1) m2acc += __shfl_xor(m2acc, mm, 64);
      if (l == 0) M2[m] = m2acc;
    } else {
      for (int n = l; n < 196; n += 16) Am[n] *= invse;
      if (l == 0) M2[m] = mx + logf(se);
    }
  }
  __syncthreads();
  if (tid == 0) {
    float mean = 0.f;
    for (int m = 0; m < 12; ++m) mean += M2[m];
    mean *= (1.0f / 12.0f);
    float zmax = -1e30f;
    for (int m = 0; m < 12; ++m) {
      float z = (M2[m] - mean) * 2.0f;
      Pv[m] = z;
      zmax = fmaxf(zmax, z);
    }
    float seP = 0.f;
    for (int m = 0; m < 12; ++m) {
      float e = __expf(Pv[m] - zmax);
      Pv[m] = e;
      seP += e;
    }
    float invP = 1.0f / seP;
    float sump = 0.f;
    for (int m = 0; m < 12; ++m) {
      float p = Pv[m] * invP;
      Pv[m] = p;
      sump += p;
    }
    ZS[0] = sump;
  }
  __syncthreads();
  for (int i = tid; i < 768; i += 256) {
    int m = i >> 6, c = i & 63;
    float a2 = 0.f;
    const float* Am = Abuf + m * 196;
    for (int n = 0; n < 196; ++n) a2 += Am[n] * TOK[SWi(n, c)];
    SQS[m * 64 + c] = a2;
  }
  __syncthreads();
  if (tid < 192) {
    int m = tid >> 4, l = tid & 15;
    float ss = 0.f;
#pragma unroll
    for (int c = l; c < 64; c += 16) {
      float v = SQS[m * 64 + c];
      ss += v * v;
    }
#pragma unroll
    for (int mm = 8; mm; mm >>= 1) ss += __shfl_xor(ss, mm, 64);
    if (l == 0) ISN[m] = 1.0f / fmaxf(sqrtf(ss), 1e-12f);
  }
  __syncthreads();
  if (tid < 64) {
    float v = 0.f;
#pragma unroll
    for (int m = 0; m < 12; ++m) v += Pv[m] * ISN[m] * SQS[m * 64 + tid];
    VV[tid] = v;
  }
  __syncthreads();
  if (tid < 47) {
    float a2 = 0.f;
#pragma unroll
    for (int q = 0; q < 16; ++q) {
      float4 w = *(const float4*)&cls_w[tid * 64 + q * 4];
      float4 v = *(const float4*)&VV[q * 4];
      a2 += w.x * v.x + w.y * v.y + w.z * v.z + w.w * v.w;
    }
    out[(size_t)b * 47 + tid] = a2 + cls_b[tid] * ZS[0];
  }
}

// ---------------------------------------------------------------------------
extern "C" void kernel_launch(void* const* d_in, const int* in_sizes, int n_in,
                              void* d_out, int out_size, void* d_ws, size_t ws_size,
                              hipStream_t stream) {
  (void)n_in; (void)out_size; (void)ws_size;
  const float* x      = (const float*)d_in[0];
  const float* conv_w = (const float*)d_in[1];
  const float* proj_w = (const float*)d_in[2];
  const float* proj_b = (const float*)d_in[3];
  const float* ln1_g  = (const float*)d_in[4];
  const float* ln1_b  = (const float*)d_in[5];
  const float* Wqkv   = (const float*)d_in[6];
  const float* bqkv   = (const float*)d_in[7];
  const float* Wo     = (const float*)d_in[8];
  const float* bo     = (const float*)d_in[9];
  const float* ln2_g  = (const float*)d_in[10];
  const float* ln2_b  = (const float*)d_in[11];
  const float* W1     = (const float*)d_in[12];
  const float* b1     = (const float*)d_in[13];
  const float* W2     = (const float*)d_in[14];
  const float* b2     = (const float*)d_in[15];
  const float* tln_g  = (const float*)d_in[16];
  const float* tln_b  = (const float*)d_in[17];
  const float* slot_q = (const float*)d_in[18];
  const float* cls_w  = (const float*)d_in[19];
  const float* cls_b  = (const float*)d_in[20];
  const int* use_spm  = (const int*)d_in[21];
  const int* spgrid   = (const int*)d_in[22];

  const int B = in_sizes[0] / 784;
  float* tokens = (float*)d_ws;

  k_conv_proj<<<B, 256, 0, stream>>>(x, conv_w, proj_w, proj_b, tokens);

  const size_t shb = 34696 * sizeof(float);  // 138,784 B
  (void)hipFuncSetAttribute((const void*)k_xformer,
                            hipFuncAttributeMaxDynamicSharedMemorySize, (int)shb);
  k_xformer<<<B, 512, shb, stream>>>(tokens, ln1_g, ln1_b, Wqkv, bqkv, Wo, bo,
                                     ln2_g, ln2_b, W1, b1, W2, b2, tln_g, tln_b);

  k_slots<<<B, 256, 0, stream>>>(tokens, slot_q, cls_w, cls_b, use_spm, spgrid,
                                 (float*)d_out);
}

// Round 3
// 831.536 us; speedup vs baseline: 9.2589x; 1.5759x over previous
//
#include <hip/hip_runtime.h>
#include <math.h>

// ---------------------------------------------------------------------------
// SlotClassifier: conv via f16 MFMA im2col -> transformer f16 MFMA -> slots f32
// tokens buffer (B x 196 x 64 f32) lives in d_ws.
// ---------------------------------------------------------------------------

typedef _Float16 half_t;
typedef __attribute__((ext_vector_type(4))) _Float16 half4;
typedef __attribute__((ext_vector_type(2))) _Float16 half2t;
typedef __attribute__((ext_vector_type(4))) float f32x4;

__device__ __forceinline__ f32x4 MFMA16(half4 a, half4 b, f32x4 c) {
  return __builtin_amdgcn_mfma_f32_16x16x16f16(a, b, c, 0, 0, 0);
}

// XOR swizzle for 64-float rows: quad index ^= (row & 15).
__device__ __forceinline__ int SWi(int row, int col) {
  return (row << 6) | (((((col >> 2) ^ row) & 15)) << 2) | (col & 3);
}
__device__ __forceinline__ int SW4i(int row, int q) {
  return (row << 6) | ((((q ^ row) & 15)) << 2);
}
// f16 rows of 64: unit = 4 f16 (8B), 16 units, unit ^= row&15.
__device__ __forceinline__ int XH(int t, int k) {
  return (t << 6) | (((((k >> 2) ^ t) & 15)) << 2) | (k & 3);
}
__device__ __forceinline__ int XH4(int t, int k4) {
  return (t << 6) | ((((k4 ^ t) & 15)) << 2);
}
__device__ __forceinline__ int KBI(int h, int n, int d) {
  return (h * 208 + n) * 20 + d;
}
__device__ __forceinline__ int VTI(int h, int d, int n) {
  return (h * 16 + d) * 212 + n;
}

__device__ __forceinline__ float gelu_exact(float v) {
  return 0.5f * v * (1.0f + erff(v * 0.7071067811865476f));
}

// ---------------------------------------------------------------------------
// Kernel A: conv1 (1->150, k9 s2 p4) + gelu + 1x1 proj, MFMA im2col GEMMs.
// one block per image, 512 threads (8 waves), 136,000 B dynamic LDS.
// LDS floats: xs[0,784) outst[784,9488) Xp(h)[9488,20304) Wc(h)[20304,28624)
//             Pw(h)[28624,34000)
// ---------------------------------------------------------------------------
__global__ __launch_bounds__(512, 1) void k_conv_proj(
    const float* __restrict__ x, const float* __restrict__ conv_w,
    const float* __restrict__ proj_w, const float* __restrict__ proj_b,
    float* __restrict__ tokens) {
  extern __shared__ float cs[];
  float* xs = cs;                      // 784
  float* outst = cs + 784;             // 8 waves x 16 x 68
  half_t* Xp = (half_t*)(cs + 9488);   // 208 x 104 f16 patches
  half_t* Wc = (half_t*)(cs + 20304);  // 160 x 104 f16 conv weights
  half_t* Pw = (half_t*)(cs + 28624);  // 64 x 168 f16 proj weights

  const int b = blockIdx.x;
  const int tid = threadIdx.x;
  const int wv = tid >> 6, ln = tid & 63, g = ln >> 4, li = ln & 15;
  const size_t base = (size_t)b * 12544;
  const half_t hz = (half_t)0.f;

  // ---- phase 1: stage input + weights, zero patch buffer ----
  for (int i = tid; i < 784; i += 512) xs[i] = x[b * 784 + i];
  for (int i = tid; i < 10816; i += 512) ((unsigned int*)Xp)[i] = 0u;
  for (int i = tid; i < 16640; i += 512) {
    int c = i / 104, t = i - c * 104;
    Wc[i] = (c < 150 && t < 81) ? (half_t)conv_w[c * 81 + t] : hz;
  }
  for (int i = tid; i < 10752; i += 512) {
    int d = i / 168, t = i - d * 168;
    Pw[i] = (t < 150) ? (half_t)proj_w[d * 150 + t] : hz;
  }
  __syncthreads();

  // ---- phase 2: im2col fill (196 pixels x 81 taps) ----
  for (int i = tid; i < 15876; i += 512) {
    int p = i / 81, t = i - p * 81;
    int ky = t / 9, kx = t - ky * 9;
    int oy = p / 14, ox = p - oy * 14;
    int iy = oy * 2 - 4 + ky, ix = ox * 2 - 4 + kx;
    float v = ((unsigned)iy < 28u && (unsigned)ix < 28u) ? xs[iy * 28 + ix] : 0.f;
    Xp[p * 104 + t] = (half_t)v;
  }
  __syncthreads();

  // ---- proj bias fragment ----
  float pb[4][4];
#pragma unroll
  for (int dt = 0; dt < 4; ++dt)
#pragma unroll
    for (int r = 0; r < 4; ++r) pb[dt][r] = proj_b[dt * 16 + g * 4 + r];

  // ---- GEMM1 (conv) -> gelu -> GEMM2 (proj), per wave per p-tile ----
  for (int pt = wv; pt < 13; pt += 8) {
    half4 bf[6];
#pragma unroll
    for (int ks = 0; ks < 6; ++ks)
      bf[ks] = *(const half4*)&Xp[(pt * 16 + li) * 104 + ks * 16 + g * 4];
    half4 hf[10];
#pragma unroll
    for (int ct = 0; ct < 10; ++ct) {
      f32x4 acc = {0.f, 0.f, 0.f, 0.f};
#pragma unroll
      for (int ks = 0; ks < 6; ++ks) {
        half4 af = *(const half4*)&Wc[(ct * 16 + li) * 104 + ks * 16 + g * 4];
        acc = MFMA16(af, bf[ks], acc);
      }
#pragma unroll
      for (int r = 0; r < 4; ++r) hf[ct][r] = (half_t)gelu_exact(acc[r]);
    }
#pragma unroll
    for (int dt = 0; dt < 4; ++dt) {
      f32x4 z = {0.f, 0.f, 0.f, 0.f};
#pragma unroll
      for (int ct = 0; ct < 10; ++ct) {
        half4 af = *(const half4*)&Pw[(dt * 16 + li) * 168 + ct * 16 + g * 4];
        z = MFMA16(af, hf[ct], z);
      }
      float4 o;
      o.x = z[0] + pb[dt][0]; o.y = z[1] + pb[dt][1];
      o.z = z[2] + pb[dt][2]; o.w = z[3] + pb[dt][3];
      // stage: row = p-in-tile (li), cols dt*16+g*4..+3  (wave-private)
      *(float4*)&outst[wv * 1088 + li * 68 + dt * 16 + g * 4] = o;
    }
    // coalesced write-out of the wave's 16x64 tile (intra-wave DS order is
    // architectural: LDS ops of one wave execute in program order)
#pragma unroll
    for (int rep = 0; rep < 4; ++rep) {
      int r4 = rep * 64 + ln;
      int row = r4 >> 4, q = r4 & 15;
      int p = pt * 16 + row;
      if (p < 196) {
        *(float4*)&tokens[base + (size_t)p * 64 + q * 4] =
            *(const float4*)&outst[wv * 1088 + row * 68 + q * 4];
      }
    }
  }
}

// ---------------------------------------------------------------------------
// Kernel B: transformer encoder layer + final LN, f16 MFMA trunk (unchanged)
// ---------------------------------------------------------------------------
__device__ __forceinline__ void ln_stats_sw(const float* __restrict__ buf,
                                            float* __restrict__ MU,
                                            float* __restrict__ RS, int tid) {
  if (tid < 196) {
    float s = 0.f;
#pragma unroll
    for (int q = 0; q < 16; ++q) {
      float4 v = *(const float4*)&buf[SW4i(tid, q)];
      s += v.x + v.y + v.z + v.w;
    }
    float mu = s * 0.015625f;
    float vs = 0.f;
#pragma unroll
    for (int q = 0; q < 16; ++q) {
      float4 v = *(const float4*)&buf[SW4i(tid, q)];
      float a = v.x - mu, b = v.y - mu, c = v.z - mu, d = v.w - mu;
      vs += a * a + b * b + c * c + d * d;
    }
    MU[tid] = mu;
    RS[tid] = rsqrtf(vs * 0.015625f + 1e-5f);
  }
}

__global__ __launch_bounds__(512, 1) void k_xformer(
    float* __restrict__ tokens,
    const float* __restrict__ ln1_g, const float* __restrict__ ln1_b,
    const float* __restrict__ Wqkv, const float* __restrict__ bqkv,
    const float* __restrict__ Wo, const float* __restrict__ bo,
    const float* __restrict__ ln2_g, const float* __restrict__ ln2_b,
    const float* __restrict__ W1, const float* __restrict__ b1,
    const float* __restrict__ W2, const float* __restrict__ b2,
    const float* __restrict__ tln_g, const float* __restrict__ tln_b) {
  extern __shared__ float smx[];
  float* T0 = smx;
  half_t* Xh = (half_t*)(smx + 12544);
  half_t* Kb = (half_t*)(smx + 19200);
  half_t* VT = (half_t*)(smx + 27520);
  float* MU = smx + 34304;
  float* RS = smx + 34500;
  half_t* Hb = (half_t*)(smx + 19200);   // alias Kb (FFN phase)
  half_t* W1c = (half_t*)(smx + 27520);  // alias VT
  half_t* W2c = (half_t*)(smx + 29568);  // alias VT + 2048 words

  const int b = blockIdx.x;
  const int tid = threadIdx.x;
  const size_t base = (size_t)b * 12544;
  const int wv = tid >> 6, ln = tid & 63, g = ln >> 4, li = ln & 15;

  for (int i = tid; i < 12544; i += 512) {
    int t = i >> 6, c = i & 63;
    T0[SWi(t, c)] = tokens[base + i];
  }
  for (int i = tid; i < 6784; i += 512) smx[27520 + i] = 0.f;
  for (int i = tid; i < 384; i += 512) smx[12544 + 6272 + i] = 0.f;
  __syncthreads();
  ln_stats_sw(T0, MU, RS, tid);
  __syncthreads();
  for (int i = tid; i < 6272; i += 512) {
    int t = i >> 5, c0 = (i & 31) * 2;
    float mu = MU[t], rs = RS[t];
    float v0 = (T0[SWi(t, c0)] - mu) * rs * ln1_g[c0] + ln1_b[c0];
    float v1 = (T0[SWi(t, c0 + 1)] - mu) * rs * ln1_g[c0 + 1] + ln1_b[c0 + 1];
    *(half2t*)&Xh[XH(t, c0)] = half2t{(half_t)v0, (half_t)v1};
  }
  __syncthreads();

  {
    const int r0 = 64 + wv * 16;
    half4 af[4];
#pragma unroll
    for (int ks = 0; ks < 4; ++ks) {
      const float* wp = &Wqkv[(r0 + li) * 64 + ks * 16 + g * 4];
      af[ks] = half4{(half_t)wp[0], (half_t)wp[1], (half_t)wp[2], (half_t)wp[3]};
    }
    float bias[4];
#pragma unroll
    for (int r = 0; r < 4; ++r) bias[r] = bqkv[r0 + g * 4 + r];
    for (int tt = 0; tt < 13; ++tt) {
      int trow = tt * 16 + li;
      f32x4 acc = {0.f, 0.f, 0.f, 0.f};
#pragma unroll
      for (int ks = 0; ks < 4; ++ks) {
        half4 bf = *(const half4*)&Xh[XH4(trow, ks * 4 + g)];
        acc = MFMA16(af[ks], bf, acc);
      }
      if (wv < 4) {
#pragma unroll
        for (int r = 0; r < 4; ++r)
          Kb[KBI(wv, trow, g * 4 + r)] = (half_t)(acc[r] + bias[r]);
      } else {
#pragma unroll
        for (int r = 0; r < 4; ++r)
          VT[VTI(wv - 4, g * 4 + r, trow)] = (half_t)(acc[r] + bias[r]);
      }
    }
  }
  half4 qf[2][4];
#pragma unroll
  for (int qi = 0; qi < 2; ++qi) {
    int qt = wv + 8 * qi;
    if (qt < 13) {
#pragma unroll
      for (int h = 0; h < 4; ++h) {
        f32x4 acc = {0.f, 0.f, 0.f, 0.f};
#pragma unroll
        for (int ks = 0; ks < 4; ++ks) {
          const float* wp = &Wqkv[(h * 16 + li) * 64 + ks * 16 + g * 4];
          half4 a = half4{(half_t)wp[0], (half_t)wp[1], (half_t)wp[2], (half_t)wp[3]};
          half4 bf = *(const half4*)&Xh[XH4(qt * 16 + li, ks * 4 + g)];
          acc = MFMA16(a, bf, acc);
        }
#pragma unroll
        for (int r = 0; r < 4; ++r)
          qf[qi][h][r] = (half_t)((acc[r] + bqkv[h * 16 + g * 4 + r]) * 0.25f);
      }
    }
  }
  __syncthreads();

#pragma unroll
  for (int qi = 0; qi < 2; ++qi) {
    int qt = wv + 8 * qi;
    if (qt < 13) {
      f32x4 z[4] = {{0.f,0.f,0.f,0.f},{0.f,0.f,0.f,0.f},{0.f,0.f,0.f,0.f},{0.f,0.f,0.f,0.f}};
#pragma unroll
      for (int h = 0; h < 4; ++h) {
        f32x4 s[13];
#pragma unroll
        for (int nt = 0; nt < 13; ++nt) {
          half4 ka = *(const half4*)&Kb[KBI(h, nt * 16 + li, g * 4)];
          f32x4 zz = {0.f, 0.f, 0.f, 0.f};
          s[nt] = MFMA16(ka, qf[qi][h], zz);
        }
        if (g > 0) { s[12][0] = -1e30f; s[12][1] = -1e30f; s[12][2] = -1e30f; s[12][3] = -1e30f; }
        float m = -1e30f;
#pragma unroll
        for (int nt = 0; nt < 13; ++nt) {
#pragma unroll
          for (int r = 0; r < 4; ++r) m = fmaxf(m, s[nt][r]);
        }
        m = fmaxf(m, __shfl_xor(m, 16, 64));
        m = fmaxf(m, __shfl_xor(m, 32, 64));
        float es = 0.f;
        half4 p[13];
#pragma unroll
        for (int nt = 0; nt < 13; ++nt) {
#pragma unroll
          for (int r = 0; r < 4; ++r) {
            float e = __expf(s[nt][r] - m);
            es += e;
            p[nt][r] = (half_t)e;
          }
        }
        es += __shfl_xor(es, 16, 64);
        es += __shfl_xor(es, 32, 64);
        f32x4 oa = {0.f, 0.f, 0.f, 0.f}, ob = {0.f, 0.f, 0.f, 0.f};
#pragma unroll
        for (int nt = 0; nt < 13; nt += 2) {
          half4 va = *(const half4*)&VT[VTI(h, li, nt * 16 + g * 4)];
          oa = MFMA16(va, p[nt], oa);
        }
#pragma unroll
        for (int nt = 1; nt < 13; nt += 2) {
          half4 va = *(const half4*)&VT[VTI(h, li, nt * 16 + g * 4)];
          ob = MFMA16(va, p[nt], ob);
        }
        float inv = 1.0f / es;
        half4 of;
#pragma unroll
        for (int r = 0; r < 4; ++r) of[r] = (half_t)((oa[r] + ob[r]) * inv);
#pragma unroll
        for (int ct = 0; ct < 4; ++ct) {
          const float* wp = &Wo[(ct * 16 + li) * 64 + h * 16 + g * 4];
          half4 wa = half4{(half_t)wp[0], (half_t)wp[1], (half_t)wp[2], (half_t)wp[3]};
          z[ct] = MFMA16(wa, of, z[ct]);
        }
      }
      int q = qt * 16 + li;
      if (q < 196) {
#pragma unroll
        for (int ct = 0; ct < 4; ++ct) {
#pragma unroll
          for (int r = 0; r < 4; ++r) T0[SWi(q, ct * 16 + g * 4 + r)] += z[ct][r];
        }
      }
    }
  }
  __syncthreads();

  for (int i = tid; i < 12544; i += 512) {
    int t = i >> 6, c = i & 63;
    T0[SWi(t, c)] += bo[c];
  }
  __syncthreads();
  ln_stats_sw(T0, MU, RS, tid);
  __syncthreads();
  for (int i = tid; i < 6272; i += 512) {
    int t = i >> 5, c0 = (i & 31) * 2;
    float mu = MU[t], rs = RS[t];
    float v0 = (T0[SWi(t, c0)] - mu) * rs * ln2_g[c0] + ln2_b[c0];
    float v1 = (T0[SWi(t, c0 + 1)] - mu) * rs * ln2_g[c0 + 1] + ln2_b[c0 + 1];
    *(half2t*)&Xh[XH(t, c0)] = half2t{(half_t)v0, (half_t)v1};
  }
  __syncthreads();

  f32x4 facc[7] = {{0.f,0.f,0.f,0.f},{0.f,0.f,0.f,0.f},{0.f,0.f,0.f,0.f},{0.f,0.f,0.f,0.f},
                   {0.f,0.f,0.f,0.f},{0.f,0.f,0.f,0.f},{0.f,0.f,0.f,0.f}};
  for (int ch = 0; ch < 4; ++ch) {
    for (int i = tid; i < 2048; i += 512) {
      int r = i >> 5, c0 = (i & 31) * 2;
      const float* wp = &W1[(ch * 64 + r) * 64 + c0];
      *(half2t*)&W1c[XH(r, c0) & 4095] = half2t{(half_t)wp[0], (half_t)wp[1]};
    }
    for (int i = tid; i < 2048; i += 512) {
      int r = i >> 5, c0 = (i & 31) * 2;
      const float* wp = &W2[r * 256 + ch * 64 + c0];
      *(half2t*)&W2c[XH(r, c0) & 4095] = half2t{(half_t)wp[0], (half_t)wp[1]};
    }
    __syncthreads();
#pragma unroll
    for (int j = 0; j < 7; ++j) {
      int u = wv + 8 * j;
      if (u < 52) {
        int mt = u >> 2, nt = u & 3;
        f32x4 acc = {0.f, 0.f, 0.f, 0.f};
#pragma unroll
        for (int ks = 0; ks < 4; ++ks) {
          half4 a = *(const half4*)&Xh[XH4(mt * 16 + li, ks * 4 + g)];
          half4 bf = *(const half4*)&W1c[XH4(nt * 16 + li, ks * 4 + g) & 4095];
          acc = MFMA16(a, bf, acc);
        }
        float bb = b1[ch * 64 + nt * 16 + li];
#pragma unroll
        for (int r = 0; r < 4; ++r)
          Hb[XH(mt * 16 + g * 4 + r, nt * 16 + li)] = (half_t)gelu_exact(acc[r] + bb);
      }
    }
    __syncthreads();
#pragma unroll
    for (int j = 0; j < 7; ++j) {
      int u = wv + 8 * j;
      if (u < 52) {
        int mt = u >> 2, nt = u & 3;
#pragma unroll
        for (int ks = 0; ks < 4; ++ks) {
          half4 a = *(const half4*)&Hb[XH4(mt * 16 + li, ks * 4 + g)];
          half4 bf = *(const half4*)&W2c[XH4(nt * 16 + li, ks * 4 + g) & 4095];
          facc[j] = MFMA16(a, bf, facc[j]);
        }
      }
    }
    __syncthreads();
  }
#pragma unroll
  for (int j = 0; j < 7; ++j) {
    int u = wv + 8 * j;
    if (u < 52) {
      int mt = u >> 2, nt = u & 3;
      int c = nt * 16 + li;
      float bb = b2[c];
#pragma unroll
      for (int r = 0; r < 4; ++r) {
        int t = mt * 16 + g * 4 + r;
        if (t < 196) T0[SWi(t, c)] += facc[j][r] + bb;
      }
    }
  }
  __syncthreads();
  ln_stats_sw(T0, MU, RS, tid);
  __syncthreads();
  for (int i = tid; i < 3136; i += 512) {
    int t = i >> 4, c0 = (i & 15) * 4;
    float4 v = *(const float4*)&T0[SW4i(t, c0 >> 2)];
    float mu = MU[t], rs = RS[t];
    float4 o;
    o.x = (v.x - mu) * rs * tln_g[c0] + tln_b[c0];
    o.y = (v.y - mu) * rs * tln_g[c0 + 1] + tln_b[c0 + 1];
    o.z = (v.z - mu) * rs * tln_g[c0 + 2] + tln_b[c0 + 2];
    o.w = (v.w - mu) * rs * tln_g[c0 + 3] + tln_b[c0 + 3];
    *(float4*)&tokens[base + t * 64 + c0] = o;
  }
}

// ---------------------------------------------------------------------------
// Kernel C: slot attention + spmask + classifier (f32, unchanged)
// ---------------------------------------------------------------------------
__global__ __launch_bounds__(256) void k_slots(
    const float* __restrict__ tokens, const float* __restrict__ slot_q,
    const float* __restrict__ cls_w, const float* __restrict__ cls_b,
    const int* __restrict__ use_spmask_p, const int* __restrict__ grid_p,
    float* __restrict__ out) {
  __shared__ float TOK[12544];
  __shared__ float Abuf[12 * 196];
  __shared__ float SQS[12 * 64];
  __shared__ float INV[196];
  __shared__ float VV[64];
  __shared__ float Pv[12];
  __shared__ float M2[12];
  __shared__ float ISN[12];
  __shared__ float ZS[2];

  const int b = blockIdx.x;
  const int tid = threadIdx.x;
  const size_t base = (size_t)b * 12544;
  (void)grid_p;

  for (int i = tid; i < 12544; i += 256) {
    int t = i >> 6, c = i & 63;
    TOK[SWi(t, c)] = tokens[base + i];
  }
  __syncthreads();
  if (tid < 196) {
    float ss = 0.f;
#pragma unroll
    for (int q = 0; q < 16; ++q) {
      float4 v = *(const float4*)&TOK[SW4i(tid, q)];
      ss += v.x * v.x + v.y * v.y + v.z * v.z + v.w * v.w;
    }
    INV[tid] = 1.0f / fmaxf(sqrtf(ss), 1e-12f);
  }
  if (tid < 192) {
    int m = tid >> 4, l = tid & 15;
    float ss = 0.f;
#pragma unroll
    for (int c = l; c < 64; c += 16) {
      float v = slot_q[m * 64 + c];
      ss += v * v;
    }
#pragma unroll
    for (int mm = 8; mm; mm >>= 1) ss += __shfl_xor(ss, mm, 64);
    float invq = 1.0f / fmaxf(sqrtf(ss), 1e-12f);
#pragma unroll
    for (int c = l; c < 64; c += 16) SQS[m * 64 + c] = slot_q[m * 64 + c] * invq;
  }
  __syncthreads();
  for (int i = tid; i < 2352; i += 256) {
    int m = i / 196, n = i - m * 196;
    float d = 0.f;
#pragma unroll
    for (int q = 0; q < 16; ++q) {
      float4 tv = *(const float4*)&TOK[SW4i(n, q)];
      float4 sv = *(const float4*)&SQS[m * 64 + q * 4];
      d += tv.x * sv.x + tv.y * sv.y + tv.z * sv.z + tv.w * sv.w;
    }
    Abuf[i] = d * INV[n] * 0.125f;
  }
  __syncthreads();
  const int use_spmask = *use_spmask_p;
  if (tid < 192) {
    int m = tid >> 4, l = tid & 15;
    float* Am = Abuf + m * 196;
    float mx = -1e30f;
    for (int n = l; n < 196; n += 16) mx = fmaxf(mx, Am[n]);
#pragma unroll
    for (int mm = 8; mm; mm >>= 1) mx = fmaxf(mx, __shfl_xor(mx, mm, 64));
    float se = 0.f, mc0 = 0.f, mc1 = 0.f, mc2 = 0.f, mc3 = 0.f;
    for (int n = l; n < 196; n += 16) {
      float e = __expf(Am[n] - mx);
      Am[n] = e;
      se += e;
      int yy = n / 14, xx = n - yy * 14;
      int cell = ((yy >= 7) ? 2 : 0) + ((xx >= 7) ? 1 : 0);
      mc0 += (cell == 0) ? e : 0.f;
      mc1 += (cell == 1) ? e : 0.f;
      mc2 += (cell == 2) ? e : 0.f;
      mc3 += (cell == 3) ? e : 0.f;
    }
#pragma unroll
    for (int mm = 8; mm; mm >>= 1) {
      se += __shfl_xor(se, mm, 64);
      mc0 += __shfl_xor(mc0, mm, 64);
      mc1 += __shfl_xor(mc1, mm, 64);
      mc2 += __shfl_xor(mc2, mm, 64);
      mc3 += __shfl_xor(mc3, mm, 64);
    }
    float invse = 1.0f / se;
    if (use_spmask) {
      int g1 = 0; float bv1 = mc0;
      if (mc1 > bv1) { bv1 = mc1; g1 = 1; }
      if (mc2 > bv1) { bv1 = mc2; g1 = 2; }
      if (mc3 > bv1) { bv1 = mc3; g1 = 3; }
      int g2 = -1; float bv2 = -1e30f;
      if (g1 != 0 && mc0 > bv2) { bv2 = mc0; g2 = 0; }
      if (g1 != 1 && mc1 > bv2) { bv2 = mc1; g2 = 1; }
      if (g1 != 2 && mc2 > bv2) { bv2 = mc2; g2 = 2; }
      if (g1 != 3 && mc3 > bv2) { bv2 = mc3; g2 = 3; }
      float sacc = 0.f;
      for (int n = l; n < 196; n += 16) {
        float a = Am[n] * invse;
        Am[n] = a;
        int yy = n / 14, xx = n - yy * 14;
        int cell = ((yy >= 7) ? 2 : 0) + ((xx >= 7) ? 1 : 0);
        sacc += (cell == g1 || cell == g2) ? a : 0.f;
      }
#pragma unroll
      for (int mm = 8; mm; mm >>= 1) sacc += __shfl_xor(sacc, mm, 64);
      float invs = 1.0f / fmaxf(sacc, 1e-8f);
      float m2acc = 0.f;
      for (int n = l; n < 196; n += 16) {
        int yy = n / 14, xx = n - yy * 14;
        int cell = ((yy >= 7) ? 2 : 0) + ((xx >= 7) ? 1 : 0);
        float a = (cell == g1 || cell == g2) ? (Am[n] * invs) : 0.f;
        Am[n] = a;
        m2acc += a;
      }
#pragma unroll
      for (int mm = 8; mm; mm >>= 1) m2acc += __shfl_xor(m2acc, mm, 64);
      if (l == 0) M2[m] = m2acc;
    } else {
      for (int n = l; n < 196; n += 16) Am[n] *= invse;
      if (l == 0) M2[m] = mx + logf(se);
    }
  }
  __syncthreads();
  if (tid == 0) {
    float mean = 0.f;
    for (int m = 0; m < 12; ++m) mean += M2[m];
    mean *= (1.0f / 12.0f);
    float zmax = -1e30f;
    for (int m = 0; m < 12; ++m) {
      float z = (M2[m] - mean) * 2.0f;
      Pv[m] = z;
      zmax = fmaxf(zmax, z);
    }
    float seP = 0.f;
    for (int m = 0; m < 12; ++m) {
      float e = __expf(Pv[m] - zmax);
      Pv[m] = e;
      seP += e;
    }
    float invP = 1.0f / seP;
    float sump = 0.f;
    for (int m = 0; m < 12; ++m) {
      float p = Pv[m] * invP;
      Pv[m] = p;
      sump += p;
    }
    ZS[0] = sump;
  }
  __syncthreads();
  for (int i = tid; i < 768; i += 256) {
    int m = i >> 6, c = i & 63;
    float a2 = 0.f;
    const float* Am = Abuf + m * 196;
    for (int n = 0; n < 196; ++n) a2 += Am[n] * TOK[SWi(n, c)];
    SQS[m * 64 + c] = a2;
  }
  __syncthreads();
  if (tid < 192) {
    int m = tid >> 4, l = tid & 15;
    float ss = 0.f;
#pragma unroll
    for (int c = l; c < 64; c += 16) {
      float v = SQS[m * 64 + c];
      ss += v * v;
    }
#pragma unroll
    for (int mm = 8; mm; mm >>= 1) ss += __shfl_xor(ss, mm, 64);
    if (l == 0) ISN[m] = 1.0f / fmaxf(sqrtf(ss), 1e-12f);
  }
  __syncthreads();
  if (tid < 64) {
    float v = 0.f;
#pragma unroll
    for (int m = 0; m < 12; ++m) v += Pv[m] * ISN[m] * SQS[m * 64 + tid];
    VV[tid] = v;
  }
  __syncthreads();
  if (tid < 47) {
    float a2 = 0.f;
#pragma unroll
    for (int q = 0; q < 16; ++q) {
      float4 w = *(const float4*)&cls_w[tid * 64 + q * 4];
      float4 v = *(const float4*)&VV[q * 4];
      a2 += w.x * v.x + w.y * v.y + w.z * v.z + w.w * v.w;
    }
    out[(size_t)b * 47 + tid] = a2 + cls_b[tid] * ZS[0];
  }
}

// ---------------------------------------------------------------------------
extern "C" void kernel_launch(void* const* d_in, const int* in_sizes, int n_in,
                              void* d_out, int out_size, void* d_ws, size_t ws_size,
                              hipStream_t stream) {
  (void)n_in; (void)out_size; (void)ws_size;
  const float* x      = (const float*)d_in[0];
  const float* conv_w = (const float*)d_in[1];
  const float* proj_w = (const float*)d_in[2];
  const float* proj_b = (const float*)d_in[3];
  const float* ln1_g  = (const float*)d_in[4];
  const float* ln1_b  = (const float*)d_in[5];
  const float* Wqkv   = (const float*)d_in[6];
  const float* bqkv   = (const float*)d_in[7];
  const float* Wo     = (const float*)d_in[8];
  const float* bo     = (const float*)d_in[9];
  const float* ln2_g  = (const float*)d_in[10];
  const float* ln2_b  = (const float*)d_in[11];
  const float* W1     = (const float*)d_in[12];
  const float* b1     = (const float*)d_in[13];
  const float* W2     = (const float*)d_in[14];
  const float* b2     = (const float*)d_in[15];
  const float* tln_g  = (const float*)d_in[16];
  const float* tln_b  = (const float*)d_in[17];
  const float* slot_q = (const float*)d_in[18];
  const float* cls_w  = (const float*)d_in[19];
  const float* cls_b  = (const float*)d_in[20];
  const int* use_spm  = (const int*)d_in[21];
  const int* spgrid   = (const int*)d_in[22];

  const int B = in_sizes[0] / 784;
  float* tokens = (float*)d_ws;

  const size_t shconv = 34000 * sizeof(float);  // 136,000 B
  (void)hipFuncSetAttribute((const void*)k_conv_proj,
                            hipFuncAttributeMaxDynamicSharedMemorySize, (int)shconv);
  k_conv_proj<<<B, 512, shconv, stream>>>(x, conv_w, proj_w, proj_b, tokens);

  const size_t shb = 34696 * sizeof(float);  // 138,784 B
  (void)hipFuncSetAttribute((const void*)k_xformer,
                            hipFuncAttributeMaxDynamicSharedMemorySize, (int)shb);
  k_xformer<<<B, 512, shb, stream>>>(tokens, ln1_g, ln1_b, Wqkv, bqkv, Wo, bo,
                                     ln2_g, ln2_b, W1, b1, W2, b2, tln_g, tln_b);

  k_slots<<<B, 256, 0, stream>>>(tokens, slot_q, cls_w, cls_b, use_spm, spgrid,
                                 (float*)d_out);
}